// Round 1
// baseline (313.274 us; speedup 1.0000x reference)
//
#include <hip/hip_runtime.h>

// Problem constants
#define B_   32
#define H_   64
#define W_   64
#define CIN  128
#define F_   256
#define K_   1152          // 3*3*128
#define M_   4096          // H*W per batch

// Padded bf16 image: [B][66][66][128]
#define HP_   66
#define XPROW (66*128)          // 8448
#define XPIMG (66*66*128)       // 557568
#define XP_ELEMS ((size_t)B_ * XPIMG)
#define XP_BYTES (XP_ELEMS * 2)                 // 35,684,352

#define WBT_BYTES ((size_t)B_ * F_ * K_ * 2)    // 18,874,368
#define FULL_WS   (WBT_BYTES + XP_BYTES + 256)
#define ZPAGE_OFF WBT_BYTES                     // old-path zero page

typedef __attribute__((ext_vector_type(8))) short bf16x8;
typedef __attribute__((ext_vector_type(4))) float f32x4;

// pack two floats -> two bf16 (round-to-nearest) in one v_perm
__device__ __forceinline__ unsigned pkbf(float a, float b) {
    unsigned ua = __builtin_bit_cast(unsigned, a) + 0x8000u;
    unsigned ub = __builtin_bit_cast(unsigned, b) + 0x8000u;
    return __builtin_amdgcn_perm(ub, ua, 0x07060302u);
}

__device__ __forceinline__ void async16(const void* g, void* l) {
    __builtin_amdgcn_global_load_lds(
        (const __attribute__((address_space(1))) unsigned int*)g,
        (__attribute__((address_space(3))) unsigned int*)l, 16, 0, 0);
}

// ---------------------------------------------------------------------------
// Kernel B: WbT[b][f][k] = bf16( W[k][f] * Werr[b][k][f] ), vectorized.
// tile 32k x 64f per block; float4 global loads; b128 global stores.
// grid = 32 * 36 * 4 = 4608 blocks, 256 threads.  (unchanged — verified)
// ---------------------------------------------------------------------------
__global__ void wbt_kernel(const float* __restrict__ W,
                           const float* __restrict__ Werr,
                           unsigned short* __restrict__ WbT,
                           unsigned int* __restrict__ zpage) {
    __shared__ float tile[32 * 68];   // stride 68: float4-aligned, low conflicts
    int bid = blockIdx.x;
    int ft   = bid & 3;
    int rest = bid >> 2;
    int kt   = rest % 36;
    int b    = rest / 36;
    int k0 = kt * 32;
    int f0 = ft * 64;
    int t  = threadIdx.x;

    if (bid == 0 && t < 64) zpage[t] = 0u;   // 256B zero page, every call

    #pragma unroll
    for (int i = 0; i < 2; ++i) {
        int c   = i * 256 + t;        // 0..511
        int kl  = c >> 4;             // 0..31
        int fl4 = c & 15;             // f offset = fl4*4
        size_t src = (size_t)(k0 + kl) * F_ + f0 + fl4 * 4;
        f32x4 w4 = *(const f32x4*)&W[src];
        f32x4 e4 = *(const f32x4*)&Werr[(size_t)b * (K_ * F_) + src];
        f32x4 v  = w4 * e4;
        *(f32x4*)&tile[kl * 68 + fl4 * 4] = v;
    }
    __syncthreads();
    {
        int c  = t;                   // 256 chunks of 8k x 1f
        int fl = c >> 2;              // 0..63
        int ku = c & 3;               // k unit of 8
        unsigned pk[4];
        #pragma unroll
        for (int j2 = 0; j2 < 4; ++j2) {
            float x0 = tile[(ku * 8 + j2 * 2 + 0) * 68 + fl];
            float x1 = tile[(ku * 8 + j2 * 2 + 1) * 68 + fl];
            pk[j2] = pkbf(x0, x1);
        }
        size_t dst = ((size_t)(b * F_ + f0 + fl)) * K_ + k0 + ku * 8;
        *(uint4*)&WbT[dst] = make_uint4(pk[0], pk[1], pk[2], pk[3]);
    }
}

// ---------------------------------------------------------------------------
// Kernel Xp: X fp32 [32][64][64][128] -> bf16 zero-padded [32][66][66][128].
// One 16B store (8 channels) per thread. grid = 8712 * 256 exactly covers it.
// Removes all halo branches / zero-page selects from the gemm A path.
// ---------------------------------------------------------------------------
__global__ void xp_kernel(const float* __restrict__ X,
                          unsigned short* __restrict__ Xp) {
    int e = blockIdx.x * 256 + threadIdx.x;   // chunk id, < 2,230,272
    int c16  = e & 15;                        // channel block of 8
    int pos  = e >> 4;                        // (b*66 + hp)*66 + wp
    int wp   = pos % 66;
    int rest = pos / 66;
    int hp   = rest % 66;
    int b    = rest / 66;
    uint4 out;
    if (hp >= 1 && hp <= 64 && wp >= 1 && wp <= 64) {
        const float* src = X + (((size_t)b * 64 + (hp - 1)) * 64 + (wp - 1)) * 128
                             + c16 * 8;
        f32x4 a = *(const f32x4*)src;
        f32x4 c = *(const f32x4*)(src + 4);
        out.x = pkbf(a[0], a[1]);  out.y = pkbf(a[2], a[3]);
        out.z = pkbf(c[0], c[1]);  out.w = pkbf(c[2], c[3]);
    } else {
        out = make_uint4(0u, 0u, 0u, 0u);
    }
    *(uint4*)&Xp[(size_t)e * 8] = out;
}

// ---------------------------------------------------------------------------
// Kernel C v2: implicit-im2col GEMM, pure global_load_lds staging (m97 shape).
// A: bf16 padded Xp via async16 (2 chunks/thread) — no VALU, no halo logic.
// B: bf16 WbT via async16 (2 chunks/thread).
// block = 256 thr (4 waves), tile 128(M) x 128(N), BK=32, 36 K-steps.
// grid = 2048; XCD-swizzled (unchanged) so WbT slices stay L2-resident.
// ---------------------------------------------------------------------------
__global__ __launch_bounds__(256, 2)
void gemm_kernel(const unsigned short* __restrict__ Xp,
                 const unsigned short* __restrict__ WbT,
                 const float* __restrict__ bias,
                 const float* __restrict__ Berr,
                 float* __restrict__ Out) {
    __shared__ unsigned short As[128 * 32];   // bf16, 8KB, rows of 64B
    __shared__ unsigned short Bs[128 * 32];   // bf16, 8KB, rows of 64B

    int bid = blockIdx.x;
    int g   = (bid & 7) | ((bid >> 8) << 3);   // 0..63
    int mt  = (bid >> 3) & 31;
    int b   = g >> 1;
    int nt  = g & 1;
    int pm0 = mt * 128;

    int t    = threadIdx.x;
    int lane = t & 63;
    int wv   = t >> 6;
    int wm   = wv >> 1;
    int wn   = wv & 1;
    int l16  = lane & 15;
    int quad = lane >> 4;

    // ---- A staging: 2 x 16B chunks per thread into linear [128][32] tile ----
    // chunk c: row ml = c>>2 (m = pm0+ml), 16B sub-chunk off = c&3 (8 bf16).
    const unsigned short* Abase[2];
    #pragma unroll
    for (int cc = 0; cc < 2; ++cc) {
        int c   = t + cc * 256;
        int ml  = c >> 2;
        int off = c & 3;
        int m   = pm0 + ml;
        int hb  = m >> 6;             // padded h base (kh=0 -> hp=hb)
        int ww  = m & 63;             // padded w base (kw=0 -> wp=ww)
        Abase[cc] = Xp + (size_t)b * XPIMG + (size_t)hb * XPROW
                       + (size_t)ww * 128 + off * 8;
    }

    // ---- B staging: 2 x 16B chunks per thread ----
    const unsigned short* wb = WbT + ((size_t)(b * F_ + nt * 128)) * K_;
    const unsigned short* Bbase[2];
    #pragma unroll
    for (int cc = 0; cc < 2; ++cc) {
        int c   = t + cc * 256;
        int nl  = c >> 2;
        int off = c & 3;
        Bbase[cc] = wb + (size_t)nl * K_ + off * 8;
    }

    f32x4 acc[4][4];
    #pragma unroll
    for (int mi = 0; mi < 4; ++mi)
        #pragma unroll
        for (int ni = 0; ni < 4; ++ni)
            acc[mi][ni] = (f32x4){0.f, 0.f, 0.f, 0.f};

    for (int kt = 0; kt < 36; ++kt) {
        int khw   = kt >> 2;
        int kh    = (khw * 11) >> 5;          // khw/3 for 0..8
        int kw    = khw - kh * 3;
        int koffA = kh * XPROW + kw * 128 + ((kt & 3) << 5);
        int koffB = kt * 32;

        if (kt) __syncthreads();              // LDS consumers of kt-1 done
        async16(Abase[0] + koffA, &As[t * 8]);
        async16(Abase[1] + koffA, &As[(t + 256) * 8]);
        async16(Bbase[0] + koffB, &Bs[t * 8]);
        async16(Bbase[1] + koffB, &Bs[(t + 256) * 8]);
        __syncthreads();                      // staging visible (vmcnt drained)

        bf16x8 af[4], bf[4];
        #pragma unroll
        for (int i = 0; i < 4; ++i) {
            af[i] = *(const bf16x8*)&As[(wm * 64 + i * 16 + l16) * 32 + quad * 8];
            bf[i] = *(const bf16x8*)&Bs[(wn * 64 + i * 16 + l16) * 32 + quad * 8];
        }
        #pragma unroll
        for (int mi = 0; mi < 4; ++mi)
            #pragma unroll
            for (int ni = 0; ni < 4; ++ni)
                acc[mi][ni] = __builtin_amdgcn_mfma_f32_16x16x32_bf16(
                    af[mi], bf[ni], acc[mi][ni], 0, 0, 0);
    }

    // ---- epilogue: + bias*Berr, ReLU, store fp32 ----
    float mb[4];
    #pragma unroll
    for (int ni = 0; ni < 4; ++ni) {
        int f = nt * 128 + wn * 64 + ni * 16 + l16;
        mb[ni] = bias[f] * Berr[b * F_ + f];
    }
    #pragma unroll
    for (int mi = 0; mi < 4; ++mi) {
        #pragma unroll
        for (int rr = 0; rr < 4; ++rr) {
            int mm = pm0 + wm * 64 + mi * 16 + quad * 4 + rr;
            float* orow = Out + ((size_t)b * M_ + mm) * F_ + nt * 128 + wn * 64;
            #pragma unroll
            for (int ni = 0; ni < 4; ++ni) {
                float v = acc[mi][ni][rr] + mb[ni];
                orow[ni * 16 + l16] = fmaxf(v, 0.0f);
            }
        }
    }
}

// ---------------------------------------------------------------------------
// Mid-tier path (previous verified 355.9us gemm): fp32 X + in-loop cvt.
// Used only when ws can hold WbT but not the padded bf16 image.
// ---------------------------------------------------------------------------
__global__ __launch_bounds__(256, 2)
void gemm_kernel_f32(const float* __restrict__ X,
                     const unsigned short* __restrict__ WbT,
                     const float* __restrict__ zpage,
                     const float* __restrict__ bias,
                     const float* __restrict__ Berr,
                     float* __restrict__ Out) {
    __shared__ unsigned short As[128 * 32];
    __shared__ unsigned short Bs[128 * 32];

    int bid = blockIdx.x;
    int g   = (bid & 7) | ((bid >> 8) << 3);
    int mt  = (bid >> 3) & 31;
    int b   = g >> 1;
    int nt  = g & 1;
    int pm0 = mt * 128;

    int t    = threadIdx.x;
    int lane = t & 63;
    int wv   = t >> 6;
    int wm   = wv >> 1;
    int wn   = wv & 1;
    int l16  = lane & 15;
    int quad = lane >> 4;

    int ml   = t >> 1;
    int half = t & 1;
    int m    = pm0 + ml;
    int hb   = m >> 6;
    int wwv  = m & 63;
    const float* Abase = X + (((size_t)b * 64 + hb - 1) * 64 + (wwv - 1)) * 128
                           + half * 16;
    unsigned vm = 0;
    #pragma unroll
    for (int khw = 0; khw < 9; ++khw) {
        int kh = (khw * 11) >> 5;
        int kw = khw - kh * 3;
        bool ok = ((unsigned)(hb + kh - 1) < 64u) && ((unsigned)(wwv + kw - 1) < 64u);
        vm |= (unsigned)ok << khw;
    }
    int ldsA = ml * 32 + half * 16;

    const unsigned short* wb = WbT + ((size_t)(b * F_ + nt * 128)) * K_;
    const unsigned short* Bbase[2];
    int ldsB[2];
    #pragma unroll
    for (int cc = 0; cc < 2; ++cc) {
        int c   = t + cc * 256;
        int nl  = c >> 2;
        int off = c & 3;
        Bbase[cc] = wb + (size_t)nl * K_ + off * 8;
        ldsB[cc]  = c * 8;
    }

    f32x4 acc[4][4];
    #pragma unroll
    for (int mi = 0; mi < 4; ++mi)
        #pragma unroll
        for (int ni = 0; ni < 4; ++ni)
            acc[mi][ni] = (f32x4){0.f, 0.f, 0.f, 0.f};

    f32x4 pr0, pr1, pr2, pr3;
    {
        const float* p = (vm & 1) ? Abase : zpage;
        pr0 = *(const f32x4*)(p);
        pr1 = *(const f32x4*)(p + 4);
        pr2 = *(const f32x4*)(p + 8);
        pr3 = *(const f32x4*)(p + 12);
    }

    for (int kt = 0; kt < 36; ++kt) {
        uint4 lo, hi;
        lo.x = pkbf(pr0[0], pr0[1]);  lo.y = pkbf(pr0[2], pr0[3]);
        lo.z = pkbf(pr1[0], pr1[1]);  lo.w = pkbf(pr1[2], pr1[3]);
        hi.x = pkbf(pr2[0], pr2[1]);  hi.y = pkbf(pr2[2], pr2[3]);
        hi.z = pkbf(pr3[0], pr3[1]);  hi.w = pkbf(pr3[2], pr3[3]);

        if (kt) __syncthreads();
        *(uint4*)&As[ldsA]     = lo;
        *(uint4*)&As[ldsA + 8] = hi;
        #pragma unroll
        for (int cc = 0; cc < 2; ++cc)
            async16(Bbase[cc] + kt * 32, &Bs[ldsB[cc]]);
        __syncthreads();

        if (kt < 35) {
            int ktn  = kt + 1;
            int khw  = ktn >> 2;
            int kh   = (khw * 11) >> 5;
            int kw   = khw - kh * 3;
            int koff = kh * 8192 + kw * 128 + ((ktn & 3) << 5);
            const float* p = ((vm >> khw) & 1) ? Abase + koff : zpage;
            pr0 = *(const f32x4*)(p);
            pr1 = *(const f32x4*)(p + 4);
            pr2 = *(const f32x4*)(p + 8);
            pr3 = *(const f32x4*)(p + 12);
        }

        bf16x8 af[4], bf[4];
        #pragma unroll
        for (int i = 0; i < 4; ++i) {
            af[i] = *(const bf16x8*)&As[(wm * 64 + i * 16 + l16) * 32 + quad * 8];
            bf[i] = *(const bf16x8*)&Bs[(wn * 64 + i * 16 + l16) * 32 + quad * 8];
        }
        #pragma unroll
        for (int mi = 0; mi < 4; ++mi)
            #pragma unroll
            for (int ni = 0; ni < 4; ++ni)
                acc[mi][ni] = __builtin_amdgcn_mfma_f32_16x16x32_bf16(
                    af[mi], bf[ni], acc[mi][ni], 0, 0, 0);
    }

    float mb[4];
    #pragma unroll
    for (int ni = 0; ni < 4; ++ni) {
        int f = nt * 128 + wn * 64 + ni * 16 + l16;
        mb[ni] = bias[f] * Berr[b * F_ + f];
    }
    #pragma unroll
    for (int mi = 0; mi < 4; ++mi) {
        #pragma unroll
        for (int rr = 0; rr < 4; ++rr) {
            int mm = pm0 + wm * 64 + mi * 16 + quad * 4 + rr;
            float* orow = Out + ((size_t)b * M_ + mm) * F_ + nt * 128 + wn * 64;
            #pragma unroll
            for (int ni = 0; ni < 4; ++ni) {
                float v = acc[mi][ni][rr] + mb[ni];
                orow[ni * 16 + l16] = fmaxf(v, 0.0f);
            }
        }
    }
}

// ---------------------------------------------------------------------------
// Zero-workspace fallback: direct conv (slow but correct), ws < 19MB only.
// ---------------------------------------------------------------------------
__global__ __launch_bounds__(256)
void fallback_kernel(const float* __restrict__ X, const float* __restrict__ W,
                     const float* __restrict__ bias, const float* __restrict__ Werr,
                     const float* __restrict__ Berr, float* __restrict__ Out) {
    __shared__ float Xs[3 * 66 * 128];
    int bid = blockIdx.x;
    int b = bid >> 6;
    int h = bid & 63;
    int t = threadIdx.x;
    int f = t;

    for (int e = t; e < 3 * 66 * 128; e += 256) {
        int kh  = e / (66 * 128);
        int rem = e - kh * 66 * 128;
        int w66 = rem >> 7;
        int c   = rem & 127;
        int hh = h + kh - 1, ww = w66 - 1;
        float v = 0.f;
        if (hh >= 0 && hh < 64 && ww >= 0 && ww < 64)
            v = X[(((size_t)b * 64 + hh) * 64 + ww) * 128 + c];
        Xs[e] = v;
    }
    __syncthreads();

    float acc[64];
    #pragma unroll
    for (int w = 0; w < 64; ++w) acc[w] = 0.f;

    for (int kk = 0; kk < 9; ++kk) {
        int kh = (kk * 11) >> 5;
        int kw = kk - kh * 3;
        for (int c = 0; c < 128; ++c) {
            size_t wi = ((size_t)kk * 128 + c) * 256 + f;
            float wvv = W[wi] * Werr[(size_t)b * (K_ * F_) + wi];
            const float* xr = &Xs[(kh * 66 + kw) * 128 + c];
            #pragma unroll
            for (int w = 0; w < 64; ++w)
                acc[w] = fmaf(xr[w * 128], wvv, acc[w]);
        }
    }
    float mb = bias[f] * Berr[b * 256 + f];
    for (int w = 0; w < 64; ++w)
        Out[(((size_t)b * 64 + h) * 64 + w) * 256 + f] = fmaxf(acc[w] + mb, 0.f);
}

// ---------------------------------------------------------------------------
extern "C" void kernel_launch(void* const* d_in, const int* in_sizes, int n_in,
                              void* d_out, int out_size, void* d_ws, size_t ws_size,
                              hipStream_t stream) {
    const float* X    = (const float*)d_in[0];
    const float* W    = (const float*)d_in[1];
    const float* bias = (const float*)d_in[2];
    const float* Werr = (const float*)d_in[3];
    const float* Berr = (const float*)d_in[4];
    float* Out = (float*)d_out;

    if (ws_size >= FULL_WS) {
        unsigned short* WbT = (unsigned short*)d_ws;
        unsigned short* Xp  = (unsigned short*)((char*)d_ws + WBT_BYTES);
        unsigned int*   zpg = (unsigned int*)((char*)d_ws + WBT_BYTES + XP_BYTES);
        wbt_kernel<<<B_ * 36 * 4, 256, 0, stream>>>(W, Werr, WbT, zpg);
        xp_kernel<<<8712, 256, 0, stream>>>(X, Xp);
        gemm_kernel<<<B_ * 32 * 2, 256, 0, stream>>>(Xp, WbT, bias, Berr, Out);
    } else if (ws_size >= WBT_BYTES + 256) {
        unsigned short* WbT  = (unsigned short*)d_ws;
        unsigned int*   zpg  = (unsigned int*)((char*)d_ws + ZPAGE_OFF);
        wbt_kernel<<<B_ * 36 * 4, 256, 0, stream>>>(W, Werr, WbT, zpg);
        gemm_kernel_f32<<<B_ * 32 * 2, 256, 0, stream>>>(X, WbT, (const float*)zpg,
                                                         bias, Berr, Out);
    } else {
        fallback_kernel<<<B_ * 64, 256, 0, stream>>>(X, W, bias, Werr, Berr, Out);
    }
}

// Round 2
// 311.226 us; speedup vs baseline: 1.0066x; 1.0066x over previous
//
#include <hip/hip_runtime.h>

// Problem constants
#define B_   32
#define H_   64
#define W_   64
#define CIN  128
#define F_   256
#define K_   1152          // 3*3*128
#define M_   4096          // H*W per batch

// Padded bf16 image: [B][66][66][128]
#define HP_   66
#define XPROW (66*128)          // 8448
#define XPIMG (66*66*128)       // 557568
#define XP_ELEMS ((size_t)B_ * XPIMG)
#define XP_BYTES (XP_ELEMS * 2)                 // 35,684,352

#define WBT_BYTES ((size_t)B_ * F_ * K_ * 2)    // 18,874,368
#define FULL_WS   (WBT_BYTES + XP_BYTES + 256)
#define ZPAGE_OFF WBT_BYTES                     // mid-tier zero page

// gemm256 geometry
#define BM_ 256
#define BK_ 64

typedef __attribute__((ext_vector_type(8))) short bf16x8;
typedef __attribute__((ext_vector_type(4))) float f32x4;

// pack two floats -> two bf16 (round-to-nearest) in one v_perm
__device__ __forceinline__ unsigned pkbf(float a, float b) {
    unsigned ua = __builtin_bit_cast(unsigned, a) + 0x8000u;
    unsigned ub = __builtin_bit_cast(unsigned, b) + 0x8000u;
    return __builtin_amdgcn_perm(ub, ua, 0x07060302u);
}

__device__ __forceinline__ void async16(const void* g, void* l) {
    __builtin_amdgcn_global_load_lds(
        (const __attribute__((address_space(1))) unsigned int*)g,
        (__attribute__((address_space(3))) unsigned int*)l, 16, 0, 0);
}

// ---------------------------------------------------------------------------
// Fused preprocessing: blocks [0,4608) do WbT, blocks [4608,13320) do Xp.
//   WbT[b][f][k] = bf16( W[k][f] * Werr[b][k][f] )
//   Xp = bf16 zero-padded X image [32][66][66][128]
// Fusing overlaps the two independent memory streams in one launch.
// ---------------------------------------------------------------------------
__global__ void prep_kernel(const float* __restrict__ W,
                            const float* __restrict__ Werr,
                            const float* __restrict__ X,
                            unsigned short* __restrict__ WbT,
                            unsigned short* __restrict__ Xp,
                            unsigned int* __restrict__ zpage) {
    __shared__ float tile[32 * 68];
    int bid = blockIdx.x;
    int t   = threadIdx.x;

    if (bid < 4608) {
        // ---- WbT body ----
        int ft   = bid & 3;
        int rest = bid >> 2;
        int kt   = rest % 36;
        int b    = rest / 36;
        int k0 = kt * 32;
        int f0 = ft * 64;

        if (bid == 0 && t < 64) zpage[t] = 0u;   // mid-tier zero page

        #pragma unroll
        for (int i = 0; i < 2; ++i) {
            int c   = i * 256 + t;        // 0..511
            int kl  = c >> 4;             // 0..31
            int fl4 = c & 15;             // f offset = fl4*4
            size_t src = (size_t)(k0 + kl) * F_ + f0 + fl4 * 4;
            f32x4 w4 = *(const f32x4*)&W[src];
            f32x4 e4 = *(const f32x4*)&Werr[(size_t)b * (K_ * F_) + src];
            f32x4 v  = w4 * e4;
            *(f32x4*)&tile[kl * 68 + fl4 * 4] = v;
        }
        __syncthreads();
        {
            int c  = t;
            int fl = c >> 2;              // 0..63
            int ku = c & 3;               // k unit of 8
            unsigned pk[4];
            #pragma unroll
            for (int j2 = 0; j2 < 4; ++j2) {
                float x0 = tile[(ku * 8 + j2 * 2 + 0) * 68 + fl];
                float x1 = tile[(ku * 8 + j2 * 2 + 1) * 68 + fl];
                pk[j2] = pkbf(x0, x1);
            }
            size_t dst = ((size_t)(b * F_ + f0 + fl)) * K_ + k0 + ku * 8;
            *(uint4*)&WbT[dst] = make_uint4(pk[0], pk[1], pk[2], pk[3]);
        }
    } else {
        // ---- Xp body ----
        int e = (bid - 4608) * 256 + t;   // chunk id, < 2,230,272
        int c16  = e & 15;                // channel block of 8
        int pos  = e >> 4;                // (b*66 + hp)*66 + wp
        int wp   = pos % 66;
        int rest = pos / 66;
        int hp   = rest % 66;
        int b    = rest / 66;
        uint4 out;
        if (hp >= 1 && hp <= 64 && wp >= 1 && wp <= 64) {
            const float* src = X + (((size_t)b * 64 + (hp - 1)) * 64 + (wp - 1)) * 128
                                 + c16 * 8;
            f32x4 a = *(const f32x4*)src;
            f32x4 c = *(const f32x4*)(src + 4);
            out.x = pkbf(a[0], a[1]);  out.y = pkbf(a[2], a[3]);
            out.z = pkbf(c[0], c[1]);  out.w = pkbf(c[2], c[3]);
        } else {
            out = make_uint4(0u, 0u, 0u, 0u);
        }
        *(uint4*)&Xp[(size_t)e * 8] = out;
    }
}

// Standalone WbT kernel for the mid-tier path (no Xp space in ws).
__global__ void wbt_kernel(const float* __restrict__ W,
                           const float* __restrict__ Werr,
                           unsigned short* __restrict__ WbT,
                           unsigned int* __restrict__ zpage) {
    __shared__ float tile[32 * 68];
    int bid = blockIdx.x;
    int ft   = bid & 3;
    int rest = bid >> 2;
    int kt   = rest % 36;
    int b    = rest / 36;
    int k0 = kt * 32;
    int f0 = ft * 64;
    int t  = threadIdx.x;

    if (bid == 0 && t < 64) zpage[t] = 0u;

    #pragma unroll
    for (int i = 0; i < 2; ++i) {
        int c   = i * 256 + t;
        int kl  = c >> 4;
        int fl4 = c & 15;
        size_t src = (size_t)(k0 + kl) * F_ + f0 + fl4 * 4;
        f32x4 w4 = *(const f32x4*)&W[src];
        f32x4 e4 = *(const f32x4*)&Werr[(size_t)b * (K_ * F_) + src];
        f32x4 v  = w4 * e4;
        *(f32x4*)&tile[kl * 68 + fl4 * 4] = v;
    }
    __syncthreads();
    {
        int c  = t;
        int fl = c >> 2;
        int ku = c & 3;
        unsigned pk[4];
        #pragma unroll
        for (int j2 = 0; j2 < 4; ++j2) {
            float x0 = tile[(ku * 8 + j2 * 2 + 0) * 68 + fl];
            float x1 = tile[(ku * 8 + j2 * 2 + 1) * 68 + fl];
            pk[j2] = pkbf(x0, x1);
        }
        size_t dst = ((size_t)(b * F_ + f0 + fl)) * K_ + k0 + ku * 8;
        *(uint4*)&WbT[dst] = make_uint4(pk[0], pk[1], pk[2], pk[3]);
    }
}

// ---------------------------------------------------------------------------
// gemm256: 256(M) x 256(N=F) tile, BK=64, 8 waves (2M x 4N), 512 thr.
// LDS 128KB: A,B each 2 x [256][64] bf16 double-buffered.
// Per K-tile: 4 phases x {ds_read frags | stage-issue | s_barrier |
// setprio(1) 16 MFMA setprio(0) | s_barrier}; single vmcnt(0) gate per
// K-tile, with next-tile loads issued 2.5 phases early (latency covered).
// T2 swizzle: stage source chunk col ^= (row&7); ds_read addr ^= (l16&7)<<4.
// Race-freedom: buffer cur^1's last ds_reads complete before the previous
// K-tile's closing barrier (compiler lgkmcnt before MFMA), and its restage
// loads are only issued after that barrier.
// grid = 512, XCD-swizzled: each XCD gets 4 whole batches (Xp[b]+WbT[b]
// ~1.7MB -> L2-resident).
// ---------------------------------------------------------------------------
__global__ __launch_bounds__(512, 2)
void gemm256_kernel(const unsigned short* __restrict__ Xp,
                    const unsigned short* __restrict__ WbT,
                    const float* __restrict__ bias,
                    const float* __restrict__ Berr,
                    float* __restrict__ Out) {
    __shared__ unsigned short As[2][BM_ * BK_];   // 2 x 32KB
    __shared__ unsigned short Bs[2][BM_ * BK_];   // 2 x 32KB

    int bid = blockIdx.x;
    int g   = (bid & 7) * 64 + (bid >> 3);   // bijective, 512 % 8 == 0
    int b   = g >> 4;                        // 0..31
    int mt  = g & 15;                        // 0..15
    int pm0 = mt * 256;

    int t    = threadIdx.x;
    int lane = t & 63;
    int wv   = t >> 6;
    int wm   = wv >> 2;       // 0..1
    int wn   = wv & 3;        // 0..3
    int l16  = lane & 15;
    int quad = lane >> 4;
    int swz  = (l16 & 7) << 4;   // byte-XOR for ds_read (bits 4-6)

    const unsigned short* XpB = Xp + (size_t)b * XPIMG;
    const unsigned short* WbB = WbT + (size_t)b * F_ * K_;

    // staging chunk state: 4 A-chunks + 4 B-chunks of 16B per thread per K-tile
    int aofs[4], bofs[4], ldst[4];
    #pragma unroll
    for (int p = 0; p < 4; ++p) {
        int c   = p * 512 + t;        // 0..2047
        int row = c >> 3;             // 0..255
        int col = c & 7;              // 16B chunk within 128B row
        int sc  = col ^ (row & 7);    // inverse-swizzled source chunk
        int m   = pm0 + row;
        int hb  = m >> 6, ww = m & 63;
        aofs[p] = hb * XPROW + ww * 128 + sc * 8;   // shorts
        bofs[p] = row * K_ + sc * 8;                // shorts
        ldst[p] = c * 8;                            // linear LDS dest (shorts)
    }

    f32x4 acc[8][4];
    #pragma unroll
    for (int mi = 0; mi < 8; ++mi)
        #pragma unroll
        for (int ni = 0; ni < 4; ++ni)
            acc[mi][ni] = (f32x4){0.f, 0.f, 0.f, 0.f};

    // ---- prologue: stage K-tile 0 into buffer 0 ----
    #pragma unroll
    for (int p = 0; p < 4; ++p)
        async16(XpB + aofs[p], &As[0][ldst[p]]);    // koffA(0) == 0
    #pragma unroll
    for (int p = 0; p < 4; ++p)
        async16(WbB + bofs[p], &Bs[0][ldst[p]]);    // koffB(0) == 0
    asm volatile("s_waitcnt vmcnt(0)" ::: "memory");
    __builtin_amdgcn_s_barrier();

    for (int kt = 0; kt < 18; ++kt) {
        const int cur = kt & 1;
        const unsigned short* Acur = As[cur];
        const unsigned short* Bcur = Bs[cur];
        unsigned short* Anxt = As[cur ^ 1];
        unsigned short* Bnxt = Bs[cur ^ 1];
        const bool pf = (kt < 17);

        // uniform source offsets for K-tile kt+1
        int ktn  = kt + 1;
        int khwN = ktn >> 1;
        int khN  = (khwN * 11) >> 5;
        int kwN  = khwN - khN * 3;
        int koA  = khN * XPROW + kwN * 128 + (ktn & 1) * 64;  // shorts
        int koB  = ktn * 64;                                   // shorts

        bf16x8 bfr[4];
        #pragma unroll
        for (int ks = 0; ks < 2; ++ks) {
            #pragma unroll
            for (int qm = 0; qm < 2; ++qm) {
                // ---- ds-read fragment subtile (buffer cur) ----
                if (qm == 0) {
                    #pragma unroll
                    for (int ni = 0; ni < 4; ++ni) {
                        int row = wn * 64 + ni * 16 + l16;
                        bfr[ni] = *(const bf16x8*)((const char*)Bcur +
                                   ((row * 128 + quad * 16 + ks * 64) ^ swz));
                    }
                }
                bf16x8 af[4];
                #pragma unroll
                for (int mi = 0; mi < 4; ++mi) {
                    int row = wm * 128 + (qm * 4 + mi) * 16 + l16;
                    af[mi] = *(const bf16x8*)((const char*)Acur +
                              ((row * 128 + quad * 16 + ks * 64) ^ swz));
                }

                // ---- stage-issue for K-tile kt+1 (phases 1-2 only) ----
                if (pf && ks == 0) {
                    if (qm == 0) {
                        #pragma unroll
                        for (int p = 0; p < 4; ++p)
                            async16(XpB + aofs[p] + koA, &Anxt[ldst[p]]);
                    } else {
                        #pragma unroll
                        for (int p = 0; p < 4; ++p)
                            async16(WbB + bofs[p] + koB, &Bnxt[ldst[p]]);
                    }
                }

                __builtin_amdgcn_s_barrier();

                __builtin_amdgcn_s_setprio(1);
                #pragma unroll
                for (int mi = 0; mi < 4; ++mi)
                    #pragma unroll
                    for (int ni = 0; ni < 4; ++ni)
                        acc[qm * 4 + mi][ni] = __builtin_amdgcn_mfma_f32_16x16x32_bf16(
                            af[mi], bfr[ni], acc[qm * 4 + mi][ni], 0, 0, 0);
                __builtin_amdgcn_s_setprio(0);

                if (ks == 1 && qm == 1) {
                    // K-tile boundary: drain next-tile staging, sync
                    if (pf) asm volatile("s_waitcnt vmcnt(0)" ::: "memory");
                    __builtin_amdgcn_s_barrier();
                } else {
                    __builtin_amdgcn_s_barrier();
                }
            }
        }
    }

    // ---- epilogue: + bias*Berr, ReLU, store fp32 ----
    float mb[4];
    #pragma unroll
    for (int ni = 0; ni < 4; ++ni) {
        int f = wn * 64 + ni * 16 + l16;
        mb[ni] = bias[f] * Berr[b * F_ + f];
    }
    #pragma unroll
    for (int mi = 0; mi < 8; ++mi) {
        #pragma unroll
        for (int rr = 0; rr < 4; ++rr) {
            int mm = pm0 + wm * 128 + mi * 16 + quad * 4 + rr;
            float* orow = Out + ((size_t)b * M_ + mm) * F_ + wn * 64;
            #pragma unroll
            for (int ni = 0; ni < 4; ++ni) {
                float v = acc[mi][ni][rr] + mb[ni];
                orow[ni * 16 + l16] = fmaxf(v, 0.0f);
            }
        }
    }
}

// ---------------------------------------------------------------------------
// Mid-tier path (verified): fp32 X + in-loop cvt, 128x128 tile.
// Used only when ws can hold WbT but not the padded bf16 image.
// ---------------------------------------------------------------------------
__global__ __launch_bounds__(256, 2)
void gemm_kernel_f32(const float* __restrict__ X,
                     const unsigned short* __restrict__ WbT,
                     const float* __restrict__ zpage,
                     const float* __restrict__ bias,
                     const float* __restrict__ Berr,
                     float* __restrict__ Out) {
    __shared__ unsigned short As[128 * 32];
    __shared__ unsigned short Bs[128 * 32];

    int bid = blockIdx.x;
    int g   = (bid & 7) | ((bid >> 8) << 3);
    int mt  = (bid >> 3) & 31;
    int b   = g >> 1;
    int nt  = g & 1;
    int pm0 = mt * 128;

    int t    = threadIdx.x;
    int lane = t & 63;
    int wv   = t >> 6;
    int wm   = wv >> 1;
    int wn   = wv & 1;
    int l16  = lane & 15;
    int quad = lane >> 4;

    int ml   = t >> 1;
    int half = t & 1;
    int m    = pm0 + ml;
    int hb   = m >> 6;
    int wwv  = m & 63;
    const float* Abase = X + (((size_t)b * 64 + hb - 1) * 64 + (wwv - 1)) * 128
                           + half * 16;
    unsigned vm = 0;
    #pragma unroll
    for (int khw = 0; khw < 9; ++khw) {
        int kh = (khw * 11) >> 5;
        int kw = khw - kh * 3;
        bool ok = ((unsigned)(hb + kh - 1) < 64u) && ((unsigned)(wwv + kw - 1) < 64u);
        vm |= (unsigned)ok << khw;
    }
    int ldsA = ml * 32 + half * 16;

    const unsigned short* wb = WbT + ((size_t)(b * F_ + nt * 128)) * K_;
    const unsigned short* Bbase[2];
    int ldsB[2];
    #pragma unroll
    for (int cc = 0; cc < 2; ++cc) {
        int c   = t + cc * 256;
        int nl  = c >> 2;
        int off = c & 3;
        Bbase[cc] = wb + (size_t)nl * K_ + off * 8;
        ldsB[cc]  = c * 8;
    }

    f32x4 acc[4][4];
    #pragma unroll
    for (int mi = 0; mi < 4; ++mi)
        #pragma unroll
        for (int ni = 0; ni < 4; ++ni)
            acc[mi][ni] = (f32x4){0.f, 0.f, 0.f, 0.f};

    f32x4 pr0, pr1, pr2, pr3;
    {
        const float* p = (vm & 1) ? Abase : zpage;
        pr0 = *(const f32x4*)(p);
        pr1 = *(const f32x4*)(p + 4);
        pr2 = *(const f32x4*)(p + 8);
        pr3 = *(const f32x4*)(p + 12);
    }

    for (int kt = 0; kt < 36; ++kt) {
        uint4 lo, hi;
        lo.x = pkbf(pr0[0], pr0[1]);  lo.y = pkbf(pr0[2], pr0[3]);
        lo.z = pkbf(pr1[0], pr1[1]);  lo.w = pkbf(pr1[2], pr1[3]);
        hi.x = pkbf(pr2[0], pr2[1]);  hi.y = pkbf(pr2[2], pr2[3]);
        hi.z = pkbf(pr3[0], pr3[1]);  hi.w = pkbf(pr3[2], pr3[3]);

        if (kt) __syncthreads();
        *(uint4*)&As[ldsA]     = lo;
        *(uint4*)&As[ldsA + 8] = hi;
        #pragma unroll
        for (int cc = 0; cc < 2; ++cc)
            async16(Bbase[cc] + kt * 32, &Bs[ldsB[cc]]);
        __syncthreads();

        if (kt < 35) {
            int ktn  = kt + 1;
            int khw  = ktn >> 2;
            int kh   = (khw * 11) >> 5;
            int kw   = khw - kh * 3;
            int koff = kh * 8192 + kw * 128 + ((ktn & 3) << 5);
            const float* p = ((vm >> khw) & 1) ? Abase + koff : zpage;
            pr0 = *(const f32x4*)(p);
            pr1 = *(const f32x4*)(p + 4);
            pr2 = *(const f32x4*)(p + 8);
            pr3 = *(const f32x4*)(p + 12);
        }

        bf16x8 af[4], bf[4];
        #pragma unroll
        for (int i = 0; i < 4; ++i) {
            af[i] = *(const bf16x8*)&As[(wm * 64 + i * 16 + l16) * 32 + quad * 8];
            bf[i] = *(const bf16x8*)&Bs[(wn * 64 + i * 16 + l16) * 32 + quad * 8];
        }
        #pragma unroll
        for (int mi = 0; mi < 4; ++mi)
            #pragma unroll
            for (int ni = 0; ni < 4; ++ni)
                acc[mi][ni] = __builtin_amdgcn_mfma_f32_16x16x32_bf16(
                    af[mi], bf[ni], acc[mi][ni], 0, 0, 0);
    }

    float mb[4];
    #pragma unroll
    for (int ni = 0; ni < 4; ++ni) {
        int f = nt * 128 + wn * 64 + ni * 16 + l16;
        mb[ni] = bias[f] * Berr[b * F_ + f];
    }
    #pragma unroll
    for (int mi = 0; mi < 4; ++mi) {
        #pragma unroll
        for (int rr = 0; rr < 4; ++rr) {
            int mm = pm0 + wm * 64 + mi * 16 + quad * 4 + rr;
            float* orow = Out + ((size_t)b * M_ + mm) * F_ + nt * 128 + wn * 64;
            #pragma unroll
            for (int ni = 0; ni < 4; ++ni) {
                float v = acc[mi][ni][rr] + mb[ni];
                orow[ni * 16 + l16] = fmaxf(v, 0.0f);
            }
        }
    }
}

// ---------------------------------------------------------------------------
// Zero-workspace fallback: direct conv (slow but correct), ws < 19MB only.
// ---------------------------------------------------------------------------
__global__ __launch_bounds__(256)
void fallback_kernel(const float* __restrict__ X, const float* __restrict__ W,
                     const float* __restrict__ bias, const float* __restrict__ Werr,
                     const float* __restrict__ Berr, float* __restrict__ Out) {
    __shared__ float Xs[3 * 66 * 128];
    int bid = blockIdx.x;
    int b = bid >> 6;
    int h = bid & 63;
    int t = threadIdx.x;
    int f = t;

    for (int e = t; e < 3 * 66 * 128; e += 256) {
        int kh  = e / (66 * 128);
        int rem = e - kh * 66 * 128;
        int w66 = rem >> 7;
        int c   = rem & 127;
        int hh = h + kh - 1, ww = w66 - 1;
        float v = 0.f;
        if (hh >= 0 && hh < 64 && ww >= 0 && ww < 64)
            v = X[(((size_t)b * 64 + hh) * 64 + ww) * 128 + c];
        Xs[e] = v;
    }
    __syncthreads();

    float acc[64];
    #pragma unroll
    for (int w = 0; w < 64; ++w) acc[w] = 0.f;

    for (int kk = 0; kk < 9; ++kk) {
        int kh = (kk * 11) >> 5;
        int kw = kk - kh * 3;
        for (int c = 0; c < 128; ++c) {
            size_t wi = ((size_t)kk * 128 + c) * 256 + f;
            float wvv = W[wi] * Werr[(size_t)b * (K_ * F_) + wi];
            const float* xr = &Xs[(kh * 66 + kw) * 128 + c];
            #pragma unroll
            for (int w = 0; w < 64; ++w)
                acc[w] = fmaf(xr[w * 128], wvv, acc[w]);
        }
    }
    float mb = bias[f] * Berr[b * 256 + f];
    for (int w = 0; w < 64; ++w)
        Out[(((size_t)b * 64 + h) * 64 + w) * 256 + f] = fmaxf(acc[w] + mb, 0.f);
}

// ---------------------------------------------------------------------------
extern "C" void kernel_launch(void* const* d_in, const int* in_sizes, int n_in,
                              void* d_out, int out_size, void* d_ws, size_t ws_size,
                              hipStream_t stream) {
    const float* X    = (const float*)d_in[0];
    const float* W    = (const float*)d_in[1];
    const float* bias = (const float*)d_in[2];
    const float* Werr = (const float*)d_in[3];
    const float* Berr = (const float*)d_in[4];
    float* Out = (float*)d_out;

    if (ws_size >= FULL_WS) {
        unsigned short* WbT = (unsigned short*)d_ws;
        unsigned short* Xp  = (unsigned short*)((char*)d_ws + WBT_BYTES);
        unsigned int*   zpg = (unsigned int*)((char*)d_ws + WBT_BYTES + XP_BYTES);
        prep_kernel<<<4608 + 8712, 256, 0, stream>>>(W, Werr, X, WbT, Xp, zpg);
        gemm256_kernel<<<512, 512, 0, stream>>>(Xp, WbT, bias, Berr, Out);
    } else if (ws_size >= WBT_BYTES + 256) {
        unsigned short* WbT  = (unsigned short*)d_ws;
        unsigned int*   zpg  = (unsigned int*)((char*)d_ws + ZPAGE_OFF);
        wbt_kernel<<<B_ * 36 * 4, 256, 0, stream>>>(W, Werr, WbT, zpg);
        gemm_kernel_f32<<<B_ * 32 * 2, 256, 0, stream>>>(X, WbT, (const float*)zpg,
                                                         bias, Berr, Out);
    } else {
        fallback_kernel<<<B_ * 64, 256, 0, stream>>>(X, W, bias, Werr, Berr, Out);
    }
}

// Round 3
// 297.017 us; speedup vs baseline: 1.0547x; 1.0478x over previous
//
#include <hip/hip_runtime.h>

// Problem constants
#define B_   32
#define H_   64
#define W_   64
#define CIN  128
#define F_   256
#define K_   1152          // 3*3*128
#define M_   4096          // H*W per batch

// Padded bf16 image: [B][66][66][128]
#define HP_   66
#define XPROW (66*128)          // 8448
#define XPIMG (66*66*128)       // 557568
#define XP_ELEMS ((size_t)B_ * XPIMG)
#define XP_BYTES (XP_ELEMS * 2)                 // 35,684,352

#define WBT_BYTES ((size_t)B_ * F_ * K_ * 2)    // 18,874,368
#define FULL_WS   (WBT_BYTES + XP_BYTES + 256)
#define ZPAGE_OFF WBT_BYTES                     // mid-tier zero page

// gemm256 geometry
#define BM_ 256
#define BK_ 64

typedef __attribute__((ext_vector_type(8))) short bf16x8;
typedef __attribute__((ext_vector_type(4))) float f32x4;

// pack two floats -> two bf16 (round-to-nearest) in one v_perm
__device__ __forceinline__ unsigned pkbf(float a, float b) {
    unsigned ua = __builtin_bit_cast(unsigned, a) + 0x8000u;
    unsigned ub = __builtin_bit_cast(unsigned, b) + 0x8000u;
    return __builtin_amdgcn_perm(ub, ua, 0x07060302u);
}

__device__ __forceinline__ void async16(const void* g, void* l) {
    __builtin_amdgcn_global_load_lds(
        (const __attribute__((address_space(1))) unsigned int*)g,
        (__attribute__((address_space(3))) unsigned int*)l, 16, 0, 0);
}

// ---------------------------------------------------------------------------
// Fused preprocessing: blocks [0,4608) do WbT, blocks [4608,13320) do Xp.
//   WbT[b][f][k] = bf16( W[k][f] * Werr[b][k][f] )
//   Xp = bf16 zero-padded X image [32][66][66][128]
// ---------------------------------------------------------------------------
__global__ void prep_kernel(const float* __restrict__ W,
                            const float* __restrict__ Werr,
                            const float* __restrict__ X,
                            unsigned short* __restrict__ WbT,
                            unsigned short* __restrict__ Xp,
                            unsigned int* __restrict__ zpage) {
    __shared__ float tile[32 * 68];
    int bid = blockIdx.x;
    int t   = threadIdx.x;

    if (bid < 4608) {
        // ---- WbT body ----
        int ft   = bid & 3;
        int rest = bid >> 2;
        int kt   = rest % 36;
        int b    = rest / 36;
        int k0 = kt * 32;
        int f0 = ft * 64;

        if (bid == 0 && t < 64) zpage[t] = 0u;   // mid-tier zero page

        #pragma unroll
        for (int i = 0; i < 2; ++i) {
            int c   = i * 256 + t;        // 0..511
            int kl  = c >> 4;             // 0..31
            int fl4 = c & 15;             // f offset = fl4*4
            size_t src = (size_t)(k0 + kl) * F_ + f0 + fl4 * 4;
            f32x4 w4 = *(const f32x4*)&W[src];
            f32x4 e4 = *(const f32x4*)&Werr[(size_t)b * (K_ * F_) + src];
            f32x4 v  = w4 * e4;
            *(f32x4*)&tile[kl * 68 + fl4 * 4] = v;
        }
        __syncthreads();
        {
            int c  = t;
            int fl = c >> 2;              // 0..63
            int ku = c & 3;               // k unit of 8
            unsigned pk[4];
            #pragma unroll
            for (int j2 = 0; j2 < 4; ++j2) {
                float x0 = tile[(ku * 8 + j2 * 2 + 0) * 68 + fl];
                float x1 = tile[(ku * 8 + j2 * 2 + 1) * 68 + fl];
                pk[j2] = pkbf(x0, x1);
            }
            size_t dst = ((size_t)(b * F_ + f0 + fl)) * K_ + k0 + ku * 8;
            *(uint4*)&WbT[dst] = make_uint4(pk[0], pk[1], pk[2], pk[3]);
        }
    } else {
        // ---- Xp body ----
        int e = (bid - 4608) * 256 + t;   // chunk id, < 2,230,272
        int c16  = e & 15;                // channel block of 8
        int pos  = e >> 4;                // (b*66 + hp)*66 + wp
        int wp   = pos % 66;
        int rest = pos / 66;
        int hp   = rest % 66;
        int b    = rest / 66;
        uint4 out;
        if (hp >= 1 && hp <= 64 && wp >= 1 && wp <= 64) {
            const float* src = X + (((size_t)b * 64 + (hp - 1)) * 64 + (wp - 1)) * 128
                                 + c16 * 8;
            f32x4 a = *(const f32x4*)src;
            f32x4 c = *(const f32x4*)(src + 4);
            out.x = pkbf(a[0], a[1]);  out.y = pkbf(a[2], a[3]);
            out.z = pkbf(c[0], c[1]);  out.w = pkbf(c[2], c[3]);
        } else {
            out = make_uint4(0u, 0u, 0u, 0u);
        }
        *(uint4*)&Xp[(size_t)e * 8] = out;
    }
}

// Standalone WbT kernel for the mid-tier path (no Xp space in ws).
__global__ void wbt_kernel(const float* __restrict__ W,
                           const float* __restrict__ Werr,
                           unsigned short* __restrict__ WbT,
                           unsigned int* __restrict__ zpage) {
    __shared__ float tile[32 * 68];
    int bid = blockIdx.x;
    int ft   = bid & 3;
    int rest = bid >> 2;
    int kt   = rest % 36;
    int b    = rest / 36;
    int k0 = kt * 32;
    int f0 = ft * 64;
    int t  = threadIdx.x;

    if (bid == 0 && t < 64) zpage[t] = 0u;

    #pragma unroll
    for (int i = 0; i < 2; ++i) {
        int c   = i * 256 + t;
        int kl  = c >> 4;
        int fl4 = c & 15;
        size_t src = (size_t)(k0 + kl) * F_ + f0 + fl4 * 4;
        f32x4 w4 = *(const f32x4*)&W[src];
        f32x4 e4 = *(const f32x4*)&Werr[(size_t)b * (K_ * F_) + src];
        f32x4 v  = w4 * e4;
        *(f32x4*)&tile[kl * 68 + fl4 * 4] = v;
    }
    __syncthreads();
    {
        int c  = t;
        int fl = c >> 2;
        int ku = c & 3;
        unsigned pk[4];
        #pragma unroll
        for (int j2 = 0; j2 < 4; ++j2) {
            float x0 = tile[(ku * 8 + j2 * 2 + 0) * 68 + fl];
            float x1 = tile[(ku * 8 + j2 * 2 + 1) * 68 + fl];
            pk[j2] = pkbf(x0, x1);
        }
        size_t dst = ((size_t)(b * F_ + f0 + fl)) * K_ + k0 + ku * 8;
        *(uint4*)&WbT[dst] = make_uint4(pk[0], pk[1], pk[2], pk[3]);
    }
}

// ---------------------------------------------------------------------------
// gemm256 v2: 256(M) x 256(N=F) tile, BK=64, 8 waves (2M x 4N), 512 thr.
// LDS 128KB: A,B each 2 x [256 rows][64 shorts] double-buffered.
// Counted-vmcnt schedule (m201-derived):
//   stage units = 64 rows x 128B (1 chunk/thread), 2 units per phase for
//   K-tile kt+1: ph(0,0):{B0,B1} ph(0,1):{B2,B3} ph(1,0):{A0,A2} ph(1,1):{A1,A3}
//   gates: vmcnt(2) end of ph(0,0)  -> A{1,3} of CURRENT tile landed
//          vmcnt(2) end of ph(1,1)  -> B-all + A{0,2} of NEXT tile landed
//   never vmcnt(0) in steady state; 2-4 phases of latency cover per load.
// WAR safety: each region's stage-issue trails its last reader by >=4
// barriers; async writes complete before readers via the gates.
// T2 swizzle both-sides (verified: 0 bank conflicts); T5 setprio on MFMA.
// grid = 512, XCD-swizzled (16 blocks sharing batch b land on one XCD).
// ---------------------------------------------------------------------------
__global__ __launch_bounds__(512, 2)
void gemm256_kernel(const unsigned short* __restrict__ Xp,
                    const unsigned short* __restrict__ WbT,
                    const float* __restrict__ bias,
                    const float* __restrict__ Berr,
                    float* __restrict__ Out) {
    __shared__ unsigned short As[2][BM_ * BK_];   // 2 x 32KB
    __shared__ unsigned short Bs[2][BM_ * BK_];   // 2 x 32KB

    int bid = blockIdx.x;
    int g   = (bid & 7) * 64 + (bid >> 3);   // bijective, 512 % 8 == 0
    int b   = g >> 4;                        // 0..31
    int mt  = g & 15;                        // 0..15
    int pm0 = mt * 256;

    int t    = threadIdx.x;
    int lane = t & 63;
    int wv   = t >> 6;
    int wm   = wv >> 2;       // 0..1
    int wn   = wv & 3;        // 0..3
    int l16  = lane & 15;
    int quad = lane >> 4;
    int swz  = (l16 & 7) << 4;   // byte-XOR for ds_read (bits 4-6)

    const unsigned short* XpB = Xp + (size_t)b * XPIMG;
    const unsigned short* WbB = WbT + (size_t)b * F_ * K_;

    // per-thread staging state: within a 64-row unit, thread t covers
    // row = base + (t>>3), 16B source chunk sc = (t&7) ^ (row&7) (inv-swizzle),
    // LDS dest = unit_base + t*16B (linear, global_load_lds-compatible).
    int tr   = t >> 3;                    // 0..63 row within unit
    int sc   = (t & 7) ^ (tr & 7);        // inverse-swizzled source chunk
    int aoff = tr * 128 + sc * 8;         // shorts within an A unit row-block
    int boff = tr * K_ + sc * 8;          // shorts within a B unit row-block
    int mbase = mt * 4;                   // A unit h-base (pm0/64)
    int ldof = t * 8;                     // shorts, per-unit LDS offset

    f32x4 acc[8][4];
    #pragma unroll
    for (int mi = 0; mi < 8; ++mi)
        #pragma unroll
        for (int ni = 0; ni < 4; ++ni)
            acc[mi][ni] = (f32x4){0.f, 0.f, 0.f, 0.f};

    auto stageA = [&](int bs, int ru, int ko) {
        async16(XpB + (size_t)(mbase + ru) * XPROW + aoff + ko,
                &As[bs][ru * 4096 + ldof]);
    };
    auto stageB = [&](int bs, int ru, int ko) {
        async16(WbB + (size_t)ru * (64 * K_) + boff + ko,
                &Bs[bs][ru * 4096 + ldof]);
    };

    // ---- prologue: stage K-tile 0 into buffer 0, ordered for the gates ----
    stageB(0, 0, 0); stageB(0, 1, 0); stageB(0, 2, 0); stageB(0, 3, 0);
    stageA(0, 0, 0); stageA(0, 2, 0); stageA(0, 1, 0); stageA(0, 3, 0);
    asm volatile("s_waitcnt vmcnt(2)" ::: "memory");   // B-all + A{0,2} landed
    __builtin_amdgcn_s_barrier();

    for (int kt = 0; kt < 18; ++kt) {
        const int cur = kt & 1;
        const int nxt = cur ^ 1;
        const unsigned short* Ac = As[cur];
        const unsigned short* Bc = Bs[cur];
        const bool pf = (kt < 17);

        // uniform source offsets for K-tile kt+1
        int ktn  = kt + 1;
        int khwN = ktn >> 1;
        int khN  = (khwN * 11) >> 5;
        int kwN  = khwN - khN * 3;
        int koA  = khN * XPROW + kwN * 128 + (ktn & 1) * 64;  // shorts
        int koB  = ktn * 64;                                   // shorts

        bf16x8 af[4], bfr[4];

        // ================= phase (ks=0, qm=0) =================
        #pragma unroll
        for (int ni = 0; ni < 4; ++ni) {
            int row = wn * 64 + ni * 16 + l16;
            bfr[ni] = *(const bf16x8*)((const char*)Bc + ((row * 128 + quad * 16) ^ swz));
        }
        #pragma unroll
        for (int mi = 0; mi < 4; ++mi) {
            int row = wm * 128 + mi * 16 + l16;
            af[mi] = *(const bf16x8*)((const char*)Ac + ((row * 128 + quad * 16) ^ swz));
        }
        if (pf) { stageB(nxt, 0, koB); stageB(nxt, 1, koB); }
        __builtin_amdgcn_s_barrier();
        __builtin_amdgcn_s_setprio(1);
        #pragma unroll
        for (int mi = 0; mi < 4; ++mi)
            #pragma unroll
            for (int ni = 0; ni < 4; ++ni)
                acc[mi][ni] = __builtin_amdgcn_mfma_f32_16x16x32_bf16(
                    af[mi], bfr[ni], acc[mi][ni], 0, 0, 0);
        __builtin_amdgcn_s_setprio(0);
        if (pf) asm volatile("s_waitcnt vmcnt(2)" ::: "memory");  // A{1,3} of kt
        else    asm volatile("s_waitcnt vmcnt(0)" ::: "memory");
        __builtin_amdgcn_s_barrier();

        // ================= phase (ks=0, qm=1) =================
        #pragma unroll
        for (int mi = 0; mi < 4; ++mi) {
            int row = wm * 128 + 64 + mi * 16 + l16;
            af[mi] = *(const bf16x8*)((const char*)Ac + ((row * 128 + quad * 16) ^ swz));
        }
        if (pf) { stageB(nxt, 2, koB); stageB(nxt, 3, koB); }
        __builtin_amdgcn_s_barrier();
        __builtin_amdgcn_s_setprio(1);
        #pragma unroll
        for (int mi = 0; mi < 4; ++mi)
            #pragma unroll
            for (int ni = 0; ni < 4; ++ni)
                acc[4 + mi][ni] = __builtin_amdgcn_mfma_f32_16x16x32_bf16(
                    af[mi], bfr[ni], acc[4 + mi][ni], 0, 0, 0);
        __builtin_amdgcn_s_setprio(0);
        __builtin_amdgcn_s_barrier();

        // ================= phase (ks=1, qm=0) =================
        #pragma unroll
        for (int ni = 0; ni < 4; ++ni) {
            int row = wn * 64 + ni * 16 + l16;
            bfr[ni] = *(const bf16x8*)((const char*)Bc + ((row * 128 + quad * 16 + 64) ^ swz));
        }
        #pragma unroll
        for (int mi = 0; mi < 4; ++mi) {
            int row = wm * 128 + mi * 16 + l16;
            af[mi] = *(const bf16x8*)((const char*)Ac + ((row * 128 + quad * 16 + 64) ^ swz));
        }
        if (pf) { stageA(nxt, 0, koA); stageA(nxt, 2, koA); }
        __builtin_amdgcn_s_barrier();
        __builtin_amdgcn_s_setprio(1);
        #pragma unroll
        for (int mi = 0; mi < 4; ++mi)
            #pragma unroll
            for (int ni = 0; ni < 4; ++ni)
                acc[mi][ni] = __builtin_amdgcn_mfma_f32_16x16x32_bf16(
                    af[mi], bfr[ni], acc[mi][ni], 0, 0, 0);
        __builtin_amdgcn_s_setprio(0);
        __builtin_amdgcn_s_barrier();

        // ================= phase (ks=1, qm=1) =================
        #pragma unroll
        for (int mi = 0; mi < 4; ++mi) {
            int row = wm * 128 + 64 + mi * 16 + l16;
            af[mi] = *(const bf16x8*)((const char*)Ac + ((row * 128 + quad * 16 + 64) ^ swz));
        }
        if (pf) { stageA(nxt, 1, koA); stageA(nxt, 3, koA); }
        __builtin_amdgcn_s_barrier();
        __builtin_amdgcn_s_setprio(1);
        #pragma unroll
        for (int mi = 0; mi < 4; ++mi)
            #pragma unroll
            for (int ni = 0; ni < 4; ++ni)
                acc[4 + mi][ni] = __builtin_amdgcn_mfma_f32_16x16x32_bf16(
                    af[mi], bfr[ni], acc[4 + mi][ni], 0, 0, 0);
        __builtin_amdgcn_s_setprio(0);
        if (pf) asm volatile("s_waitcnt vmcnt(2)" ::: "memory");  // B-all+A{0,2} of kt+1
        __builtin_amdgcn_s_barrier();
    }

    // ---- epilogue: + bias*Berr, ReLU, store fp32 ----
    float mb[4];
    #pragma unroll
    for (int ni = 0; ni < 4; ++ni) {
        int f = wn * 64 + ni * 16 + l16;
        mb[ni] = bias[f] * Berr[b * F_ + f];
    }
    #pragma unroll
    for (int mi = 0; mi < 8; ++mi) {
        #pragma unroll
        for (int rr = 0; rr < 4; ++rr) {
            int mm = pm0 + wm * 128 + mi * 16 + quad * 4 + rr;
            float* orow = Out + ((size_t)b * M_ + mm) * F_ + wn * 64;
            #pragma unroll
            for (int ni = 0; ni < 4; ++ni) {
                float v = acc[mi][ni][rr] + mb[ni];
                orow[ni * 16 + l16] = fmaxf(v, 0.0f);
            }
        }
    }
}

// ---------------------------------------------------------------------------
// Mid-tier path (verified): fp32 X + in-loop cvt, 128x128 tile.
// ---------------------------------------------------------------------------
__global__ __launch_bounds__(256, 2)
void gemm_kernel_f32(const float* __restrict__ X,
                     const unsigned short* __restrict__ WbT,
                     const float* __restrict__ zpage,
                     const float* __restrict__ bias,
                     const float* __restrict__ Berr,
                     float* __restrict__ Out) {
    __shared__ unsigned short As[128 * 32];
    __shared__ unsigned short Bs[128 * 32];

    int bid = blockIdx.x;
    int g   = (bid & 7) | ((bid >> 8) << 3);
    int mt  = (bid >> 3) & 31;
    int b   = g >> 1;
    int nt  = g & 1;
    int pm0 = mt * 128;

    int t    = threadIdx.x;
    int lane = t & 63;
    int wv   = t >> 6;
    int wm   = wv >> 1;
    int wn   = wv & 1;
    int l16  = lane & 15;
    int quad = lane >> 4;

    int ml   = t >> 1;
    int half = t & 1;
    int m    = pm0 + ml;
    int hb   = m >> 6;
    int wwv  = m & 63;
    const float* Abase = X + (((size_t)b * 64 + hb - 1) * 64 + (wwv - 1)) * 128
                           + half * 16;
    unsigned vm = 0;
    #pragma unroll
    for (int khw = 0; khw < 9; ++khw) {
        int kh = (khw * 11) >> 5;
        int kw = khw - kh * 3;
        bool ok = ((unsigned)(hb + kh - 1) < 64u) && ((unsigned)(wwv + kw - 1) < 64u);
        vm |= (unsigned)ok << khw;
    }
    int ldsA = ml * 32 + half * 16;

    const unsigned short* wb = WbT + ((size_t)(b * F_ + nt * 128)) * K_;
    const unsigned short* Bbase[2];
    int ldsB[2];
    #pragma unroll
    for (int cc = 0; cc < 2; ++cc) {
        int c   = t + cc * 256;
        int nl  = c >> 2;
        int off = c & 3;
        Bbase[cc] = wb + (size_t)nl * K_ + off * 8;
        ldsB[cc]  = c * 8;
    }

    f32x4 acc[4][4];
    #pragma unroll
    for (int mi = 0; mi < 4; ++mi)
        #pragma unroll
        for (int ni = 0; ni < 4; ++ni)
            acc[mi][ni] = (f32x4){0.f, 0.f, 0.f, 0.f};

    f32x4 pr0, pr1, pr2, pr3;
    {
        const float* p = (vm & 1) ? Abase : zpage;
        pr0 = *(const f32x4*)(p);
        pr1 = *(const f32x4*)(p + 4);
        pr2 = *(const f32x4*)(p + 8);
        pr3 = *(const f32x4*)(p + 12);
    }

    for (int kt = 0; kt < 36; ++kt) {
        uint4 lo, hi;
        lo.x = pkbf(pr0[0], pr0[1]);  lo.y = pkbf(pr0[2], pr0[3]);
        lo.z = pkbf(pr1[0], pr1[1]);  lo.w = pkbf(pr1[2], pr1[3]);
        hi.x = pkbf(pr2[0], pr2[1]);  hi.y = pkbf(pr2[2], pr2[3]);
        hi.z = pkbf(pr3[0], pr3[1]);  hi.w = pkbf(pr3[2], pr3[3]);

        if (kt) __syncthreads();
        *(uint4*)&As[ldsA]     = lo;
        *(uint4*)&As[ldsA + 8] = hi;
        #pragma unroll
        for (int cc = 0; cc < 2; ++cc)
            async16(Bbase[cc] + kt * 32, &Bs[ldsB[cc]]);
        __syncthreads();

        if (kt < 35) {
            int ktn  = kt + 1;
            int khw  = ktn >> 2;
            int kh   = (khw * 11) >> 5;
            int kw   = khw - kh * 3;
            int koff = kh * 8192 + kw * 128 + ((ktn & 3) << 5);
            const float* p = ((vm >> khw) & 1) ? Abase + koff : zpage;
            pr0 = *(const f32x4*)(p);
            pr1 = *(const f32x4*)(p + 4);
            pr2 = *(const f32x4*)(p + 8);
            pr3 = *(const f32x4*)(p + 12);
        }

        bf16x8 af[4], bf[4];
        #pragma unroll
        for (int i = 0; i < 4; ++i) {
            af[i] = *(const bf16x8*)&As[(wm * 64 + i * 16 + l16) * 32 + quad * 8];
            bf[i] = *(const bf16x8*)&Bs[(wn * 64 + i * 16 + l16) * 32 + quad * 8];
        }
        #pragma unroll
        for (int mi = 0; mi < 4; ++mi)
            #pragma unroll
            for (int ni = 0; ni < 4; ++ni)
                acc[mi][ni] = __builtin_amdgcn_mfma_f32_16x16x32_bf16(
                    af[mi], bf[ni], acc[mi][ni], 0, 0, 0);
    }

    float mb[4];
    #pragma unroll
    for (int ni = 0; ni < 4; ++ni) {
        int f = nt * 128 + wn * 64 + ni * 16 + l16;
        mb[ni] = bias[f] * Berr[b * F_ + f];
    }
    #pragma unroll
    for (int mi = 0; mi < 4; ++mi) {
        #pragma unroll
        for (int rr = 0; rr < 4; ++rr) {
            int mm = pm0 + wm * 64 + mi * 16 + quad * 4 + rr;
            float* orow = Out + ((size_t)b * M_ + mm) * F_ + nt * 128 + wn * 64;
            #pragma unroll
            for (int ni = 0; ni < 4; ++ni) {
                float v = acc[mi][ni][rr] + mb[ni];
                orow[ni * 16 + l16] = fmaxf(v, 0.0f);
            }
        }
    }
}

// ---------------------------------------------------------------------------
// Zero-workspace fallback: direct conv (slow but correct), ws < 19MB only.
// ---------------------------------------------------------------------------
__global__ __launch_bounds__(256)
void fallback_kernel(const float* __restrict__ X, const float* __restrict__ W,
                     const float* __restrict__ bias, const float* __restrict__ Werr,
                     const float* __restrict__ Berr, float* __restrict__ Out) {
    __shared__ float Xs[3 * 66 * 128];
    int bid = blockIdx.x;
    int b = bid >> 6;
    int h = bid & 63;
    int t = threadIdx.x;
    int f = t;

    for (int e = t; e < 3 * 66 * 128; e += 256) {
        int kh  = e / (66 * 128);
        int rem = e - kh * 66 * 128;
        int w66 = rem >> 7;
        int c   = rem & 127;
        int hh = h + kh - 1, ww = w66 - 1;
        float v = 0.f;
        if (hh >= 0 && hh < 64 && ww >= 0 && ww < 64)
            v = X[(((size_t)b * 64 + hh) * 64 + ww) * 128 + c];
        Xs[e] = v;
    }
    __syncthreads();

    float acc[64];
    #pragma unroll
    for (int w = 0; w < 64; ++w) acc[w] = 0.f;

    for (int kk = 0; kk < 9; ++kk) {
        int kh = (kk * 11) >> 5;
        int kw = kk - kh * 3;
        for (int c = 0; c < 128; ++c) {
            size_t wi = ((size_t)kk * 128 + c) * 256 + f;
            float wvv = W[wi] * Werr[(size_t)b * (K_ * F_) + wi];
            const float* xr = &Xs[(kh * 66 + kw) * 128 + c];
            #pragma unroll
            for (int w = 0; w < 64; ++w)
                acc[w] = fmaf(xr[w * 128], wvv, acc[w]);
        }
    }
    float mb = bias[f] * Berr[b * 256 + f];
    for (int w = 0; w < 64; ++w)
        Out[(((size_t)b * 64 + h) * 64 + w) * 256 + f] = fmaxf(acc[w] + mb, 0.f);
}

// ---------------------------------------------------------------------------
extern "C" void kernel_launch(void* const* d_in, const int* in_sizes, int n_in,
                              void* d_out, int out_size, void* d_ws, size_t ws_size,
                              hipStream_t stream) {
    const float* X    = (const float*)d_in[0];
    const float* W    = (const float*)d_in[1];
    const float* bias = (const float*)d_in[2];
    const float* Werr = (const float*)d_in[3];
    const float* Berr = (const float*)d_in[4];
    float* Out = (float*)d_out;

    if (ws_size >= FULL_WS) {
        unsigned short* WbT = (unsigned short*)d_ws;
        unsigned short* Xp  = (unsigned short*)((char*)d_ws + WBT_BYTES);
        unsigned int*   zpg = (unsigned int*)((char*)d_ws + WBT_BYTES + XP_BYTES);
        prep_kernel<<<4608 + 8712, 256, 0, stream>>>(W, Werr, X, WbT, Xp, zpg);
        gemm256_kernel<<<512, 512, 0, stream>>>(Xp, WbT, bias, Berr, Out);
    } else if (ws_size >= WBT_BYTES + 256) {
        unsigned short* WbT  = (unsigned short*)d_ws;
        unsigned int*   zpg  = (unsigned int*)((char*)d_ws + ZPAGE_OFF);
        wbt_kernel<<<B_ * 36 * 4, 256, 0, stream>>>(W, Werr, WbT, zpg);
        gemm_kernel_f32<<<B_ * 32 * 2, 256, 0, stream>>>(X, WbT, (const float*)zpg,
                                                         bias, Berr, Out);
    } else {
        fallback_kernel<<<B_ * 64, 256, 0, stream>>>(X, W, bias, Werr, Berr, Out);
    }
}

// Round 4
// 289.278 us; speedup vs baseline: 1.0830x; 1.0268x over previous
//
#include <hip/hip_runtime.h>

// Problem constants
#define B_   32
#define H_   64
#define W_   64
#define CIN  128
#define F_   256
#define K_   1152          // 3*3*128
#define M_   4096          // H*W per batch

// Padded bf16 image: [B][66][66][128]
#define HP_   66
#define XPROW (66*128)          // 8448
#define XPIMG (66*66*128)       // 557568
#define XP_ELEMS ((size_t)B_ * XPIMG)
#define XP_BYTES (XP_ELEMS * 2)                 // 35,684,352

#define WBT_BYTES ((size_t)B_ * F_ * K_ * 2)    // 18,874,368
#define FULL_WS   (WBT_BYTES + XP_BYTES + 256)
#define ZPAGE_OFF WBT_BYTES                     // mid-tier zero page

// gemm256 geometry
#define BM_ 256
#define BK_ 64

typedef __attribute__((ext_vector_type(8))) short bf16x8;
typedef __attribute__((ext_vector_type(4))) float f32x4;

// pack two floats -> two bf16 (round-to-nearest) in one v_perm
__device__ __forceinline__ unsigned pkbf(float a, float b) {
    unsigned ua = __builtin_bit_cast(unsigned, a) + 0x8000u;
    unsigned ub = __builtin_bit_cast(unsigned, b) + 0x8000u;
    return __builtin_amdgcn_perm(ub, ua, 0x07060302u);
}

__device__ __forceinline__ void async16(const void* g, void* l) {
    __builtin_amdgcn_global_load_lds(
        (const __attribute__((address_space(1))) unsigned int*)g,
        (__attribute__((address_space(3))) unsigned int*)l, 16, 0, 0);
}

// ---------------------------------------------------------------------------
// Fused preprocessing: blocks [0,4608) do WbT, blocks [4608,13320) do Xp.
//   WbT[b][f][k] = bf16( W[k][f] * Werr[b][k][f] )
//   Xp = bf16 zero-padded X image [32][66][66][128]
// ---------------------------------------------------------------------------
__global__ void prep_kernel(const float* __restrict__ W,
                            const float* __restrict__ Werr,
                            const float* __restrict__ X,
                            unsigned short* __restrict__ WbT,
                            unsigned short* __restrict__ Xp,
                            unsigned int* __restrict__ zpage) {
    __shared__ float tile[32 * 68];
    int bid = blockIdx.x;
    int t   = threadIdx.x;

    if (bid < 4608) {
        // ---- WbT body ----
        int ft   = bid & 3;
        int rest = bid >> 2;
        int kt   = rest % 36;
        int b    = rest / 36;
        int k0 = kt * 32;
        int f0 = ft * 64;

        if (bid == 0 && t < 64) zpage[t] = 0u;   // mid-tier zero page

        #pragma unroll
        for (int i = 0; i < 2; ++i) {
            int c   = i * 256 + t;        // 0..511
            int kl  = c >> 4;             // 0..31
            int fl4 = c & 15;             // f offset = fl4*4
            size_t src = (size_t)(k0 + kl) * F_ + f0 + fl4 * 4;
            f32x4 w4 = *(const f32x4*)&W[src];
            f32x4 e4 = *(const f32x4*)&Werr[(size_t)b * (K_ * F_) + src];
            f32x4 v  = w4 * e4;
            *(f32x4*)&tile[kl * 68 + fl4 * 4] = v;
        }
        __syncthreads();
        {
            int c  = t;
            int fl = c >> 2;              // 0..63
            int ku = c & 3;               // k unit of 8
            unsigned pk[4];
            #pragma unroll
            for (int j2 = 0; j2 < 4; ++j2) {
                float x0 = tile[(ku * 8 + j2 * 2 + 0) * 68 + fl];
                float x1 = tile[(ku * 8 + j2 * 2 + 1) * 68 + fl];
                pk[j2] = pkbf(x0, x1);
            }
            size_t dst = ((size_t)(b * F_ + f0 + fl)) * K_ + k0 + ku * 8;
            *(uint4*)&WbT[dst] = make_uint4(pk[0], pk[1], pk[2], pk[3]);
        }
    } else {
        // ---- Xp body ----
        int e = (bid - 4608) * 256 + t;   // chunk id, < 2,230,272
        int c16  = e & 15;                // channel block of 8
        int pos  = e >> 4;                // (b*66 + hp)*66 + wp
        int wp   = pos % 66;
        int rest = pos / 66;
        int hp   = rest % 66;
        int b    = rest / 66;
        uint4 out;
        if (hp >= 1 && hp <= 64 && wp >= 1 && wp <= 64) {
            const float* src = X + (((size_t)b * 64 + (hp - 1)) * 64 + (wp - 1)) * 128
                                 + c16 * 8;
            f32x4 a = *(const f32x4*)src;
            f32x4 c = *(const f32x4*)(src + 4);
            out.x = pkbf(a[0], a[1]);  out.y = pkbf(a[2], a[3]);
            out.z = pkbf(c[0], c[1]);  out.w = pkbf(c[2], c[3]);
        } else {
            out = make_uint4(0u, 0u, 0u, 0u);
        }
        *(uint4*)&Xp[(size_t)e * 8] = out;
    }
}

// Standalone WbT kernel for the mid-tier path (no Xp space in ws).
__global__ void wbt_kernel(const float* __restrict__ W,
                           const float* __restrict__ Werr,
                           unsigned short* __restrict__ WbT,
                           unsigned int* __restrict__ zpage) {
    __shared__ float tile[32 * 68];
    int bid = blockIdx.x;
    int ft   = bid & 3;
    int rest = bid >> 2;
    int kt   = rest % 36;
    int b    = rest / 36;
    int k0 = kt * 32;
    int f0 = ft * 64;
    int t  = threadIdx.x;

    if (bid == 0 && t < 64) zpage[t] = 0u;

    #pragma unroll
    for (int i = 0; i < 2; ++i) {
        int c   = i * 256 + t;
        int kl  = c >> 4;
        int fl4 = c & 15;
        size_t src = (size_t)(k0 + kl) * F_ + f0 + fl4 * 4;
        f32x4 w4 = *(const f32x4*)&W[src];
        f32x4 e4 = *(const f32x4*)&Werr[(size_t)b * (K_ * F_) + src];
        f32x4 v  = w4 * e4;
        *(f32x4*)&tile[kl * 68 + fl4 * 4] = v;
    }
    __syncthreads();
    {
        int c  = t;
        int fl = c >> 2;
        int ku = c & 3;
        unsigned pk[4];
        #pragma unroll
        for (int j2 = 0; j2 < 4; ++j2) {
            float x0 = tile[(ku * 8 + j2 * 2 + 0) * 68 + fl];
            float x1 = tile[(ku * 8 + j2 * 2 + 1) * 68 + fl];
            pk[j2] = pkbf(x0, x1);
        }
        size_t dst = ((size_t)(b * F_ + f0 + fl)) * K_ + k0 + ku * 8;
        *(uint4*)&WbT[dst] = make_uint4(pk[0], pk[1], pk[2], pk[3]);
    }
}

// ---------------------------------------------------------------------------
// gemm256 v3: 256(M) x 256(N=F) tile, BK=64, 8 waves (2M x 4N), 512 thr.
// LDS 128KB: A,B each 2 x [256 rows][64 shorts] double-buffered.
// TWO barriers per K-tile (both are counted-vmcnt gates); waves free-run
// within each part so one wave's ds_reads overlap another's MFMAs:
//   entry state: cur{B0-3,A0,A2} visible; cur{A1,A3} in flight (2 outst.)
//   part1: read khalf0/qm0 frags; issue B0-3(nxt); 16 MFMA
//   G2: vmcnt(4) -> drains cur{A1,A3} (issued 1 full tile ago); barrier
//   part2: read rest of cur; issue A0,A2,A1,A3(nxt); 48 MFMA
//   G1: vmcnt(2) -> drains nxt{B0-3,A0,A2}; leaves nxt{A1,A3}; barrier
// Within-tile safety: reads hit cur only, stage-writes hit nxt only; WAR
// on nxt is ordered by the entry barrier. sched_barrier(0) after each
// barrier pins gated ds_reads (rule #18). T2 swizzle both-sides (0
// conflicts, verified); T5 setprio on MFMA clusters.
// grid = 512, XCD-swizzled (16 blocks sharing batch b on one XCD).
// ---------------------------------------------------------------------------
__global__ __launch_bounds__(512, 2)
void gemm256_kernel(const unsigned short* __restrict__ Xp,
                    const unsigned short* __restrict__ WbT,
                    const float* __restrict__ bias,
                    const float* __restrict__ Berr,
                    float* __restrict__ Out) {
    __shared__ unsigned short As[2][BM_ * BK_];   // 2 x 32KB
    __shared__ unsigned short Bs[2][BM_ * BK_];   // 2 x 32KB

    int bid = blockIdx.x;
    int g   = (bid & 7) * 64 + (bid >> 3);   // bijective, 512 % 8 == 0
    int b   = g >> 4;                        // 0..31
    int mt  = g & 15;                        // 0..15
    int pm0 = mt * 256;

    int t    = threadIdx.x;
    int lane = t & 63;
    int wv   = t >> 6;
    int wm   = wv >> 2;       // 0..1
    int wn   = wv & 3;        // 0..3
    int l16  = lane & 15;
    int quad = lane >> 4;
    int swz  = (l16 & 7) << 4;   // byte-XOR for ds_read (bits 4-6)

    const unsigned short* XpB = Xp + (size_t)b * XPIMG;
    const unsigned short* WbB = WbT + (size_t)b * F_ * K_;

    // per-thread staging state: within a 64-row unit, thread t covers
    // row = base + (t>>3), 16B source chunk sc = (t&7) ^ (row&7) (inv-swizzle),
    // LDS dest = unit_base + t*16B (linear, global_load_lds-compatible).
    int tr   = t >> 3;                    // 0..63 row within unit
    int sc   = (t & 7) ^ (tr & 7);        // inverse-swizzled source chunk
    int aoff = tr * 128 + sc * 8;         // shorts within an A unit row-block
    int boff = tr * K_ + sc * 8;          // shorts within a B unit row-block
    int mbase = mt * 4;                   // A unit h-base (pm0/64)
    int ldof = t * 8;                     // shorts, per-unit LDS offset

    f32x4 acc[8][4];
    #pragma unroll
    for (int mi = 0; mi < 8; ++mi)
        #pragma unroll
        for (int ni = 0; ni < 4; ++ni)
            acc[mi][ni] = (f32x4){0.f, 0.f, 0.f, 0.f};

    auto stageA = [&](int bs, int ru, int ko) {
        async16(XpB + (size_t)(mbase + ru) * XPROW + aoff + ko,
                &As[bs][ru * 4096 + ldof]);
    };
    auto stageB = [&](int bs, int ru, int ko) {
        async16(WbB + (size_t)ru * (64 * K_) + boff + ko,
                &Bs[bs][ru * 4096 + ldof]);
    };

    // ---- prologue: stage K-tile 0 into buffer 0, ordered for the gates ----
    stageB(0, 0, 0); stageB(0, 1, 0); stageB(0, 2, 0); stageB(0, 3, 0);
    stageA(0, 0, 0); stageA(0, 2, 0); stageA(0, 1, 0); stageA(0, 3, 0);
    asm volatile("s_waitcnt vmcnt(2)" ::: "memory");   // B-all + A{0,2} landed
    __builtin_amdgcn_s_barrier();
    __builtin_amdgcn_sched_barrier(0);

    for (int kt = 0; kt < 18; ++kt) {
        const int cur = kt & 1;
        const int nxt = cur ^ 1;
        const unsigned short* Ac = As[cur];
        const unsigned short* Bc = Bs[cur];
        const bool pf = (kt < 17);

        // uniform source offsets for K-tile kt+1
        int ktn  = kt + 1;
        int khwN = ktn >> 1;
        int khN  = (khwN * 11) >> 5;
        int kwN  = khwN - khN * 3;
        int koA  = khN * XPROW + kwN * 128 + (ktn & 1) * 64;  // shorts
        int koB  = ktn * 64;                                   // shorts

        // ================= part 1: khalf0, qm0 (16 MFMA) =================
        bf16x8 b0[4], a0[4];
        #pragma unroll
        for (int ni = 0; ni < 4; ++ni) {
            int row = wn * 64 + ni * 16 + l16;
            b0[ni] = *(const bf16x8*)((const char*)Bc + ((row * 128 + quad * 16) ^ swz));
        }
        #pragma unroll
        for (int mi = 0; mi < 4; ++mi) {
            int row = wm * 128 + mi * 16 + l16;
            a0[mi] = *(const bf16x8*)((const char*)Ac + ((row * 128 + quad * 16) ^ swz));
        }
        if (pf) {
            stageB(nxt, 0, koB); stageB(nxt, 1, koB);
            stageB(nxt, 2, koB); stageB(nxt, 3, koB);
        }
        __builtin_amdgcn_s_setprio(1);
        #pragma unroll
        for (int mi = 0; mi < 4; ++mi)
            #pragma unroll
            for (int ni = 0; ni < 4; ++ni)
                acc[mi][ni] = __builtin_amdgcn_mfma_f32_16x16x32_bf16(
                    a0[mi], b0[ni], acc[mi][ni], 0, 0, 0);
        __builtin_amdgcn_s_setprio(0);

        // ---- gate G2: cur{A1,A3} visible (issued a full K-tile ago) ----
        if (pf) asm volatile("s_waitcnt vmcnt(4)" ::: "memory");
        else    asm volatile("s_waitcnt vmcnt(0)" ::: "memory");
        __builtin_amdgcn_s_barrier();
        __builtin_amdgcn_sched_barrier(0);

        // ================= part 2a: khalf0, qm1 (16 MFMA) =================
        bf16x8 a1[4];
        #pragma unroll
        for (int mi = 0; mi < 4; ++mi) {
            int row = wm * 128 + 64 + mi * 16 + l16;
            a1[mi] = *(const bf16x8*)((const char*)Ac + ((row * 128 + quad * 16) ^ swz));
        }
        if (pf) {
            stageA(nxt, 0, koA); stageA(nxt, 2, koA);
            stageA(nxt, 1, koA); stageA(nxt, 3, koA);
        }
        __builtin_amdgcn_s_setprio(1);
        #pragma unroll
        for (int mi = 0; mi < 4; ++mi)
            #pragma unroll
            for (int ni = 0; ni < 4; ++ni)
                acc[4 + mi][ni] = __builtin_amdgcn_mfma_f32_16x16x32_bf16(
                    a1[mi], b0[ni], acc[4 + mi][ni], 0, 0, 0);
        __builtin_amdgcn_s_setprio(0);

        // ================= part 2b: khalf1, qm0+qm1 (32 MFMA) =================
        bf16x8 b1[4], a2[4], a3[4];
        #pragma unroll
        for (int ni = 0; ni < 4; ++ni) {
            int row = wn * 64 + ni * 16 + l16;
            b1[ni] = *(const bf16x8*)((const char*)Bc + ((row * 128 + quad * 16 + 64) ^ swz));
        }
        #pragma unroll
        for (int mi = 0; mi < 4; ++mi) {
            int row = wm * 128 + mi * 16 + l16;
            a2[mi] = *(const bf16x8*)((const char*)Ac + ((row * 128 + quad * 16 + 64) ^ swz));
        }
        #pragma unroll
        for (int mi = 0; mi < 4; ++mi) {
            int row = wm * 128 + 64 + mi * 16 + l16;
            a3[mi] = *(const bf16x8*)((const char*)Ac + ((row * 128 + quad * 16 + 64) ^ swz));
        }
        __builtin_amdgcn_s_setprio(1);
        #pragma unroll
        for (int mi = 0; mi < 4; ++mi)
            #pragma unroll
            for (int ni = 0; ni < 4; ++ni)
                acc[mi][ni] = __builtin_amdgcn_mfma_f32_16x16x32_bf16(
                    a2[mi], b1[ni], acc[mi][ni], 0, 0, 0);
        #pragma unroll
        for (int mi = 0; mi < 4; ++mi)
            #pragma unroll
            for (int ni = 0; ni < 4; ++ni)
                acc[4 + mi][ni] = __builtin_amdgcn_mfma_f32_16x16x32_bf16(
                    a3[mi], b1[ni], acc[4 + mi][ni], 0, 0, 0);
        __builtin_amdgcn_s_setprio(0);

        // ---- gate G1: nxt{B0-3,A0,A2} visible; nxt{A1,A3} stay in flight ----
        if (pf) {
            asm volatile("s_waitcnt vmcnt(2)" ::: "memory");
            __builtin_amdgcn_s_barrier();
            __builtin_amdgcn_sched_barrier(0);
        }
    }

    // ---- epilogue: + bias*Berr, ReLU, store fp32 ----
    float mb[4];
    #pragma unroll
    for (int ni = 0; ni < 4; ++ni) {
        int f = wn * 64 + ni * 16 + l16;
        mb[ni] = bias[f] * Berr[b * F_ + f];
    }
    #pragma unroll
    for (int mi = 0; mi < 8; ++mi) {
        #pragma unroll
        for (int rr = 0; rr < 4; ++rr) {
            int mm = pm0 + wm * 128 + mi * 16 + quad * 4 + rr;
            float* orow = Out + ((size_t)b * M_ + mm) * F_ + wn * 64;
            #pragma unroll
            for (int ni = 0; ni < 4; ++ni) {
                float v = acc[mi][ni][rr] + mb[ni];
                orow[ni * 16 + l16] = fmaxf(v, 0.0f);
            }
        }
    }
}

// ---------------------------------------------------------------------------
// Mid-tier path (verified): fp32 X + in-loop cvt, 128x128 tile.
// ---------------------------------------------------------------------------
__global__ __launch_bounds__(256, 2)
void gemm_kernel_f32(const float* __restrict__ X,
                     const unsigned short* __restrict__ WbT,
                     const float* __restrict__ zpage,
                     const float* __restrict__ bias,
                     const float* __restrict__ Berr,
                     float* __restrict__ Out) {
    __shared__ unsigned short As[128 * 32];
    __shared__ unsigned short Bs[128 * 32];

    int bid = blockIdx.x;
    int g   = (bid & 7) | ((bid >> 8) << 3);
    int mt  = (bid >> 3) & 31;
    int b   = g >> 1;
    int nt  = g & 1;
    int pm0 = mt * 128;

    int t    = threadIdx.x;
    int lane = t & 63;
    int wv   = t >> 6;
    int wm   = wv >> 1;
    int wn   = wv & 1;
    int l16  = lane & 15;
    int quad = lane >> 4;

    int ml   = t >> 1;
    int half = t & 1;
    int m    = pm0 + ml;
    int hb   = m >> 6;
    int wwv  = m & 63;
    const float* Abase = X + (((size_t)b * 64 + hb - 1) * 64 + (wwv - 1)) * 128
                           + half * 16;
    unsigned vm = 0;
    #pragma unroll
    for (int khw = 0; khw < 9; ++khw) {
        int kh = (khw * 11) >> 5;
        int kw = khw - kh * 3;
        bool ok = ((unsigned)(hb + kh - 1) < 64u) && ((unsigned)(wwv + kw - 1) < 64u);
        vm |= (unsigned)ok << khw;
    }
    int ldsA = ml * 32 + half * 16;

    const unsigned short* wb = WbT + ((size_t)(b * F_ + nt * 128)) * K_;
    const unsigned short* Bbase[2];
    int ldsB[2];
    #pragma unroll
    for (int cc = 0; cc < 2; ++cc) {
        int c   = t + cc * 256;
        int nl  = c >> 2;
        int off = c & 3;
        Bbase[cc] = wb + (size_t)nl * K_ + off * 8;
        ldsB[cc]  = c * 8;
    }

    f32x4 acc[4][4];
    #pragma unroll
    for (int mi = 0; mi < 4; ++mi)
        #pragma unroll
        for (int ni = 0; ni < 4; ++ni)
            acc[mi][ni] = (f32x4){0.f, 0.f, 0.f, 0.f};

    f32x4 pr0, pr1, pr2, pr3;
    {
        const float* p = (vm & 1) ? Abase : zpage;
        pr0 = *(const f32x4*)(p);
        pr1 = *(const f32x4*)(p + 4);
        pr2 = *(const f32x4*)(p + 8);
        pr3 = *(const f32x4*)(p + 12);
    }

    for (int kt = 0; kt < 36; ++kt) {
        uint4 lo, hi;
        lo.x = pkbf(pr0[0], pr0[1]);  lo.y = pkbf(pr0[2], pr0[3]);
        lo.z = pkbf(pr1[0], pr1[1]);  lo.w = pkbf(pr1[2], pr1[3]);
        hi.x = pkbf(pr2[0], pr2[1]);  hi.y = pkbf(pr2[2], pr2[3]);
        hi.z = pkbf(pr3[0], pr3[1]);  hi.w = pkbf(pr3[2], pr3[3]);

        if (kt) __syncthreads();
        *(uint4*)&As[ldsA]     = lo;
        *(uint4*)&As[ldsA + 8] = hi;
        #pragma unroll
        for (int cc = 0; cc < 2; ++cc)
            async16(Bbase[cc] + kt * 32, &Bs[ldsB[cc]]);
        __syncthreads();

        if (kt < 35) {
            int ktn  = kt + 1;
            int khw  = ktn >> 2;
            int kh   = (khw * 11) >> 5;
            int kw   = khw - kh * 3;
            int koff = kh * 8192 + kw * 128 + ((ktn & 3) << 5);
            const float* p = ((vm >> khw) & 1) ? Abase + koff : zpage;
            pr0 = *(const f32x4*)(p);
            pr1 = *(const f32x4*)(p + 4);
            pr2 = *(const f32x4*)(p + 8);
            pr3 = *(const f32x4*)(p + 12);
        }

        bf16x8 af[4], bf[4];
        #pragma unroll
        for (int i = 0; i < 4; ++i) {
            af[i] = *(const bf16x8*)&As[(wm * 64 + i * 16 + l16) * 32 + quad * 8];
            bf[i] = *(const bf16x8*)&Bs[(wn * 64 + i * 16 + l16) * 32 + quad * 8];
        }
        #pragma unroll
        for (int mi = 0; mi < 4; ++mi)
            #pragma unroll
            for (int ni = 0; ni < 4; ++ni)
                acc[mi][ni] = __builtin_amdgcn_mfma_f32_16x16x32_bf16(
                    af[mi], bf[ni], acc[mi][ni], 0, 0, 0);
    }

    float mb[4];
    #pragma unroll
    for (int ni = 0; ni < 4; ++ni) {
        int f = nt * 128 + wn * 64 + ni * 16 + l16;
        mb[ni] = bias[f] * Berr[b * F_ + f];
    }
    #pragma unroll
    for (int mi = 0; mi < 4; ++mi) {
        #pragma unroll
        for (int rr = 0; rr < 4; ++rr) {
            int mm = pm0 + wm * 64 + mi * 16 + quad * 4 + rr;
            float* orow = Out + ((size_t)b * M_ + mm) * F_ + nt * 128 + wn * 64;
            #pragma unroll
            for (int ni = 0; ni < 4; ++ni) {
                float v = acc[mi][ni][rr] + mb[ni];
                orow[ni * 16 + l16] = fmaxf(v, 0.0f);
            }
        }
    }
}

// ---------------------------------------------------------------------------
// Zero-workspace fallback: direct conv (slow but correct), ws < 19MB only.
// ---------------------------------------------------------------------------
__global__ __launch_bounds__(256)
void fallback_kernel(const float* __restrict__ X, const float* __restrict__ W,
                     const float* __restrict__ bias, const float* __restrict__ Werr,
                     const float* __restrict__ Berr, float* __restrict__ Out) {
    __shared__ float Xs[3 * 66 * 128];
    int bid = blockIdx.x;
    int b = bid >> 6;
    int h = bid & 63;
    int t = threadIdx.x;
    int f = t;

    for (int e = t; e < 3 * 66 * 128; e += 256) {
        int kh  = e / (66 * 128);
        int rem = e - kh * 66 * 128;
        int w66 = rem >> 7;
        int c   = rem & 127;
        int hh = h + kh - 1, ww = w66 - 1;
        float v = 0.f;
        if (hh >= 0 && hh < 64 && ww >= 0 && ww < 64)
            v = X[(((size_t)b * 64 + hh) * 64 + ww) * 128 + c];
        Xs[e] = v;
    }
    __syncthreads();

    float acc[64];
    #pragma unroll
    for (int w = 0; w < 64; ++w) acc[w] = 0.f;

    for (int kk = 0; kk < 9; ++kk) {
        int kh = (kk * 11) >> 5;
        int kw = kk - kh * 3;
        for (int c = 0; c < 128; ++c) {
            size_t wi = ((size_t)kk * 128 + c) * 256 + f;
            float wvv = W[wi] * Werr[(size_t)b * (K_ * F_) + wi];
            const float* xr = &Xs[(kh * 66 + kw) * 128 + c];
            #pragma unroll
            for (int w = 0; w < 64; ++w)
                acc[w] = fmaf(xr[w * 128], wvv, acc[w]);
        }
    }
    float mb = bias[f] * Berr[b * 256 + f];
    for (int w = 0; w < 64; ++w)
        Out[(((size_t)b * 64 + h) * 64 + w) * 256 + f] = fmaxf(acc[w] + mb, 0.f);
}

// ---------------------------------------------------------------------------
extern "C" void kernel_launch(void* const* d_in, const int* in_sizes, int n_in,
                              void* d_out, int out_size, void* d_ws, size_t ws_size,
                              hipStream_t stream) {
    const float* X    = (const float*)d_in[0];
    const float* W    = (const float*)d_in[1];
    const float* bias = (const float*)d_in[2];
    const float* Werr = (const float*)d_in[3];
    const float* Berr = (const float*)d_in[4];
    float* Out = (float*)d_out;

    if (ws_size >= FULL_WS) {
        unsigned short* WbT = (unsigned short*)d_ws;
        unsigned short* Xp  = (unsigned short*)((char*)d_ws + WBT_BYTES);
        unsigned int*   zpg = (unsigned int*)((char*)d_ws + WBT_BYTES + XP_BYTES);
        prep_kernel<<<4608 + 8712, 256, 0, stream>>>(W, Werr, X, WbT, Xp, zpg);
        gemm256_kernel<<<512, 512, 0, stream>>>(Xp, WbT, bias, Berr, Out);
    } else if (ws_size >= WBT_BYTES + 256) {
        unsigned short* WbT  = (unsigned short*)d_ws;
        unsigned int*   zpg  = (unsigned int*)((char*)d_ws + ZPAGE_OFF);
        wbt_kernel<<<B_ * 36 * 4, 256, 0, stream>>>(W, Werr, WbT, zpg);
        gemm_kernel_f32<<<B_ * 32 * 2, 256, 0, stream>>>(X, WbT, (const float*)zpg,
                                                         bias, Berr, Out);
    } else {
        fallback_kernel<<<B_ * 64, 256, 0, stream>>>(X, W, bias, Werr, Berr, Out);
    }
}